// Round 1
// baseline (451.234 us; speedup 1.0000x reference)
//
#include <hip/hip_runtime.h>
#include <math.h>

#define H 1024
#define F 2048
#define V 50257

// ws layout (floats):
//   [0     .. 2048)  attn logits
//   [2048  .. 3072)  attn_applied (zeroed by k_softmax, accumulated by atomicAdd)
//   [3072  .. 4096)  x (combine+relu output)
//   [4096  .. 5120)  h_new (16B-aligned copy; d_out+V is not float4-aligned)
//   [5120  .. 5120+V) vocab logits
//   [55380 .. 55382) log-softmax stats {max, log(sum)}
#define WS_ATTNL   0
#define WS_APPLIED 2048
#define WS_X       3072
#define WS_HNEW    4096
#define WS_LOGITS  5120
#define WS_STATS   55380

__device__ __forceinline__ float wave_sum(float v) {
    #pragma unroll
    for (int off = 32; off > 0; off >>= 1) v += __shfl_xor(v, off, 64);
    return v;
}

__device__ __forceinline__ float dot4(float4 a, float4 b) {
    return a.x * b.x + a.y * b.y + a.z * b.z + a.w * b.w;
}

// attn logits: one wave per row f of attn_W [F, 2H]; cat1 = [emb[tok], hidden]
__global__ void k_attn(const int* __restrict__ tok_p, const float* __restrict__ hidden,
                       const float* __restrict__ emb, const float* __restrict__ attn_W,
                       const float* __restrict__ attn_b, float* __restrict__ logits) {
    const int wv = threadIdx.x >> 6, lane = threadIdx.x & 63;
    const int f = blockIdx.x * 4 + wv;
    const int tok = tok_p[0];
    const float4* e4 = (const float4*)(emb + (size_t)tok * H);
    const float4* h4 = (const float4*)hidden;
    const float4* row = (const float4*)(attn_W + (size_t)f * (2 * H));
    float acc = 0.f;
    #pragma unroll
    for (int k = lane; k < H / 4; k += 64) acc += dot4(e4[k], row[k]);
    #pragma unroll
    for (int k = lane; k < H / 4; k += 64) acc += dot4(h4[k], row[H / 4 + k]);
    acc = wave_sum(acc);
    if (lane == 0) logits[f] = acc + attn_b[f];
}

// softmax over F=2048 (single block, 1024 threads); also zero-inits applied[]
__global__ void k_softmax(const float* __restrict__ logits, float* __restrict__ weights,
                          float* __restrict__ applied) {
    __shared__ float red[16];
    __shared__ float bc;
    const int t = threadIdx.x, lane = t & 63, wv = t >> 6;
    applied[t] = 0.f;  // t covers [0,1024) == H
    float x0 = logits[t], x1 = logits[t + 1024];
    float m = fmaxf(x0, x1);
    #pragma unroll
    for (int off = 32; off > 0; off >>= 1) m = fmaxf(m, __shfl_xor(m, off, 64));
    if (lane == 0) red[wv] = m;
    __syncthreads();
    if (t == 0) { float M = red[0]; for (int w = 1; w < 16; ++w) M = fmaxf(M, red[w]); bc = M; }
    __syncthreads();
    const float M = bc;
    float e0 = expf(x0 - M), e1 = expf(x1 - M);
    float s = wave_sum(e0 + e1);
    if (lane == 0) red[wv] = s;
    __syncthreads();
    if (t == 0) { float S = red[0]; for (int w = 1; w < 16; ++w) S += red[w]; bc = 1.f / S; }
    __syncthreads();
    const float inv = bc;
    weights[t] = e0 * inv;
    weights[t + 1024] = e1 * inv;
}

// attn_applied[h] = sum_f w[f] * enc[f,h].  grid (H/256, F/32), block 256.
__global__ void k_attnapply(const float* __restrict__ weights, const float* __restrict__ enc,
                            float* __restrict__ applied) {
    const int h = blockIdx.x * 256 + threadIdx.x;
    const int f0 = blockIdx.y * 32;
    float acc = 0.f;
    #pragma unroll 8
    for (int f = f0; f < f0 + 32; ++f) acc += weights[f] * enc[(size_t)f * H + h];
    atomicAdd(&applied[h], acc);
}

// x = relu(cat2 @ comb_W.T + comb_b); cat2 = [emb[tok], applied]. wave/row.
__global__ void k_comb(const int* __restrict__ tok_p, const float* __restrict__ emb,
                       const float* __restrict__ applied, const float* __restrict__ comb_W,
                       const float* __restrict__ comb_b, float* __restrict__ x) {
    const int wv = threadIdx.x >> 6, lane = threadIdx.x & 63;
    const int i = blockIdx.x * 4 + wv;
    const int tok = tok_p[0];
    const float4* e4 = (const float4*)(emb + (size_t)tok * H);
    const float4* a4 = (const float4*)applied;
    const float4* row = (const float4*)(comb_W + (size_t)i * (2 * H));
    float acc = 0.f;
    #pragma unroll
    for (int k = lane; k < H / 4; k += 64) acc += dot4(e4[k], row[k]);
    #pragma unroll
    for (int k = lane; k < H / 4; k += 64) acc += dot4(a4[k], row[H / 4 + k]);
    acc = wave_sum(acc);
    if (lane == 0) x[i] = fmaxf(acc + comb_b[i], 0.f);
}

// GRU step: one wave per output element i computes all 6 dot products.
__global__ void k_gru(const float* __restrict__ x, const float* __restrict__ hidden,
                      const float* __restrict__ W_ih, const float* __restrict__ W_hh,
                      const float* __restrict__ b_ih, const float* __restrict__ b_hh,
                      float* __restrict__ hnew_out, float* __restrict__ hnew_ws) {
    const int wv = threadIdx.x >> 6, lane = threadIdx.x & 63;
    const int i = blockIdx.x * 4 + wv;
    const float4* x4 = (const float4*)x;
    const float4* h4 = (const float4*)hidden;
    const float4* wri = (const float4*)(W_ih + (size_t)i * H);
    const float4* wzi = (const float4*)(W_ih + (size_t)(H + i) * H);
    const float4* wni = (const float4*)(W_ih + (size_t)(2 * H + i) * H);
    const float4* wrh = (const float4*)(W_hh + (size_t)i * H);
    const float4* wzh = (const float4*)(W_hh + (size_t)(H + i) * H);
    const float4* wnh = (const float4*)(W_hh + (size_t)(2 * H + i) * H);
    float ar = 0.f, az = 0.f, an = 0.f, br = 0.f, bz = 0.f, bn = 0.f;
    #pragma unroll
    for (int k = lane; k < H / 4; k += 64) {
        float4 xv = x4[k], hv = h4[k];
        ar += dot4(xv, wri[k]);
        az += dot4(xv, wzi[k]);
        an += dot4(xv, wni[k]);
        br += dot4(hv, wrh[k]);
        bz += dot4(hv, wzh[k]);
        bn += dot4(hv, wnh[k]);
    }
    ar = wave_sum(ar); az = wave_sum(az); an = wave_sum(an);
    br = wave_sum(br); bz = wave_sum(bz); bn = wave_sum(bn);
    if (lane == 0) {
        float r = 1.f / (1.f + expf(-((ar + b_ih[i]) + (br + b_hh[i]))));
        float z = 1.f / (1.f + expf(-((az + b_ih[H + i]) + (bz + b_hh[H + i]))));
        float n = tanhf((an + b_ih[2 * H + i]) + r * (bn + b_hh[2 * H + i]));
        float hn = (1.f - z) * n + z * hidden[i];
        hnew_out[i] = hn;
        hnew_ws[i] = hn;
    }
}

// vocab logits: one wave per row v of out_W [V, H]
__global__ void k_out(const float* __restrict__ hnew, const float* __restrict__ out_W,
                      const float* __restrict__ out_b, float* __restrict__ logits) {
    const int wv = threadIdx.x >> 6, lane = threadIdx.x & 63;
    const int v = blockIdx.x * 4 + wv;
    if (v >= V) return;
    const float4* h4 = (const float4*)hnew;
    const float4* row = (const float4*)(out_W + (size_t)v * H);
    float acc = 0.f;
    #pragma unroll
    for (int k = lane; k < H / 4; k += 64) acc += dot4(h4[k], row[k]);
    acc = wave_sum(acc);
    if (lane == 0) logits[v] = acc + out_b[v];
}

// log-softmax stats over V (single block, online max/sum)
__global__ void k_lsmreduce(const float* __restrict__ logits, float* __restrict__ stats) {
    __shared__ float sm[16], sl[16];
    const int t = threadIdx.x, lane = t & 63, wv = t >> 6;
    float m = -INFINITY, l = 0.f;
    for (int v = t; v < V; v += 1024) {
        float xv = logits[v];
        float mn = fmaxf(m, xv);
        l = l * expf(m - mn) + expf(xv - mn);
        m = mn;
    }
    #pragma unroll
    for (int off = 32; off > 0; off >>= 1) {
        float mo = __shfl_xor(m, off, 64);
        float lo = __shfl_xor(l, off, 64);
        float mn = fmaxf(m, mo);
        l = l * expf(m - mn) + lo * expf(mo - mn);
        m = mn;
    }
    if (lane == 0) { sm[wv] = m; sl[wv] = l; }
    __syncthreads();
    if (t == 0) {
        float M = sm[0], L = sl[0];
        for (int w = 1; w < 16; ++w) {
            float mn = fmaxf(M, sm[w]);
            L = L * expf(M - mn) + sl[w] * expf(sm[w] - mn);
            M = mn;
        }
        stats[0] = M;
        stats[1] = logf(L);
    }
}

__global__ void k_lsmwrite(const float* __restrict__ logits, const float* __restrict__ stats,
                           float* __restrict__ out) {
    const int v = blockIdx.x * 256 + threadIdx.x;
    if (v < V) out[v] = logits[v] - stats[0] - stats[1];
}

extern "C" void kernel_launch(void* const* d_in, const int* in_sizes, int n_in,
                              void* d_out, int out_size, void* d_ws, size_t ws_size,
                              hipStream_t stream) {
    const int*   tok    = (const int*)d_in[0];
    const float* hidden = (const float*)d_in[1];
    const float* enc    = (const float*)d_in[2];
    const float* emb    = (const float*)d_in[3];
    const float* attn_W = (const float*)d_in[4];
    const float* attn_b = (const float*)d_in[5];
    const float* comb_W = (const float*)d_in[6];
    const float* comb_b = (const float*)d_in[7];
    const float* W_ih   = (const float*)d_in[8];
    const float* W_hh   = (const float*)d_in[9];
    const float* b_ih   = (const float*)d_in[10];
    const float* b_hh   = (const float*)d_in[11];
    const float* out_W  = (const float*)d_in[12];
    const float* out_b  = (const float*)d_in[13];

    float* out        = (float*)d_out;              // [V] log-softmax
    float* out_hnew   = (float*)d_out + V;          // [H]
    float* out_attnw  = (float*)d_out + V + H;      // [F]
    float* ws         = (float*)d_ws;

    k_attn<<<F / 4, 256, 0, stream>>>(tok, hidden, emb, attn_W, attn_b, ws + WS_ATTNL);
    k_softmax<<<1, 1024, 0, stream>>>(ws + WS_ATTNL, out_attnw, ws + WS_APPLIED);
    k_attnapply<<<dim3(H / 256, F / 32), 256, 0, stream>>>(out_attnw, enc, ws + WS_APPLIED);
    k_comb<<<H / 4, 256, 0, stream>>>(tok, emb, ws + WS_APPLIED, comb_W, comb_b, ws + WS_X);
    k_gru<<<H / 4, 256, 0, stream>>>(ws + WS_X, hidden, W_ih, W_hh, b_ih, b_hh,
                                     out_hnew, ws + WS_HNEW);
    k_out<<<(V + 3) / 4, 256, 0, stream>>>(ws + WS_HNEW, out_W, out_b, ws + WS_LOGITS);
    k_lsmreduce<<<1, 1024, 0, stream>>>(ws + WS_LOGITS, ws + WS_STATS);
    k_lsmwrite<<<(V + 255) / 256, 256, 0, stream>>>(ws + WS_LOGITS, ws + WS_STATS, out);
}

// Round 2
// 431.299 us; speedup vs baseline: 1.0462x; 1.0462x over previous
//
#include <hip/hip_runtime.h>
#include <math.h>

#define H 1024
#define F 2048
#define V 50257

// ws layout (float offsets); [0..3200) is zeroed by hipMemsetAsync each launch.
#define WS_ASUM    0      // [64]  attn exp-sum slots
#define WS_OSUM    64     // [64]  vocab exp-sum slots
#define WS_EXPW    128    // [F]   unnormalized attn weights exp(logit)
#define WS_APPLIED 2176   // [H]   attn_applied accumulator (atomics)
#define WS_X       3200   // [H]   combine+relu output
#define WS_HNEW    4224   // [H]   h_new (16B-aligned copy)
#define WS_GH      5248   // [3H]  h @ W_hh.T + b_hh
#define WS_LOGITS  8320   // [V]   vocab logits

__device__ __forceinline__ float wave_sum(float v) {
    #pragma unroll
    for (int off = 32; off > 0; off >>= 1) v += __shfl_xor(v, off, 64);
    return v;
}

__device__ __forceinline__ float dot4(float4 a, float4 b) {
    return a.x * b.x + a.y * b.y + a.z * b.z + a.w * b.w;
}

// K1: fused  [attn logits -> exp -> slot-atomic sum]  (blocks 0..511, wave/row)
//        ||  [gh = h @ W_hh.T + b_hh]                 (blocks 512..1279, wave/row)
__global__ void k1_attn_gh(const int* __restrict__ tok_p, const float* __restrict__ hidden,
                           const float* __restrict__ emb, const float* __restrict__ attn_W,
                           const float* __restrict__ attn_b, const float* __restrict__ W_hh,
                           const float* __restrict__ b_hh, float* __restrict__ ws) {
    const int wv = threadIdx.x >> 6, lane = threadIdx.x & 63;
    const int bid = blockIdx.x;
    const float4* h4 = (const float4*)hidden;
    if (bid < F / 4) {
        __shared__ float se[4];
        const int f = bid * 4 + wv;
        const int tok = tok_p[0];
        const float4* e4 = (const float4*)(emb + (size_t)tok * H);
        const float4* row = (const float4*)(attn_W + (size_t)f * (2 * H));
        float acc = 0.f;
        #pragma unroll
        for (int k = lane; k < H / 4; k += 64)
            acc += dot4(e4[k], row[k]) + dot4(h4[k], row[H / 4 + k]);
        acc = wave_sum(acc);
        if (lane == 0) {
            float e = expf(acc + attn_b[f]);
            ws[WS_EXPW + f] = e;
            se[wv] = e;
        }
        __syncthreads();
        if (threadIdx.x == 0)
            atomicAdd(&ws[WS_ASUM + (bid & 63)], se[0] + se[1] + se[2] + se[3]);
    } else {
        const int i = (bid - F / 4) * 4 + wv;   // [0, 3H)
        const float4* row = (const float4*)(W_hh + (size_t)i * H);
        float acc = 0.f;
        #pragma unroll
        for (int k = lane; k < H / 4; k += 64) acc += dot4(h4[k], row[k]);
        acc = wave_sum(acc);
        if (lane == 0) ws[WS_GH + i] = acc + b_hh[i];
    }
}

// K2: applied[h] += (1/sum) * sum_f expw[f]*enc[f,h]; also writes normalized attn weights.
__global__ void k2_apply(const float* __restrict__ enc, float* __restrict__ ws,
                         float* __restrict__ out_attnw) {
    const int h = blockIdx.x * 256 + threadIdx.x;
    const int f0 = blockIdx.y * 32;
    float s = 0.f;
    #pragma unroll
    for (int j = 0; j < 64; ++j) s += ws[WS_ASUM + j];
    const float inv = 1.f / s;
    float acc = 0.f;
    #pragma unroll 8
    for (int f = f0; f < f0 + 32; ++f) acc += ws[WS_EXPW + f] * enc[(size_t)f * H + h];
    atomicAdd(&ws[WS_APPLIED + h], acc * inv);
    if (blockIdx.x == 0 && threadIdx.x < 32) {
        int f = f0 + threadIdx.x;
        out_attnw[f] = ws[WS_EXPW + f] * inv;
    }
}

// K3: x = relu([emb[tok], applied] @ comb_W.T + comb_b), wave/row
__global__ void k3_comb(const int* __restrict__ tok_p, const float* __restrict__ emb,
                        const float* __restrict__ comb_W, const float* __restrict__ comb_b,
                        float* __restrict__ ws) {
    const int wv = threadIdx.x >> 6, lane = threadIdx.x & 63;
    const int i = blockIdx.x * 4 + wv;
    const int tok = tok_p[0];
    const float4* e4 = (const float4*)(emb + (size_t)tok * H);
    const float4* a4 = (const float4*)(ws + WS_APPLIED);
    const float4* row = (const float4*)(comb_W + (size_t)i * (2 * H));
    float acc = 0.f;
    #pragma unroll
    for (int k = lane; k < H / 4; k += 64)
        acc += dot4(e4[k], row[k]) + dot4(a4[k], row[H / 4 + k]);
    acc = wave_sum(acc);
    if (lane == 0) ws[WS_X + i] = fmaxf(acc + comb_b[i], 0.f);
}

// K4: gx = x @ W_ih.T; gates with precomputed gh; h_new. Wave per output i.
__global__ void k4_gru(const float* __restrict__ hidden, const float* __restrict__ W_ih,
                       const float* __restrict__ b_ih, float* __restrict__ ws,
                       float* __restrict__ hnew_out) {
    const int wv = threadIdx.x >> 6, lane = threadIdx.x & 63;
    const int i = blockIdx.x * 4 + wv;
    const float4* x4 = (const float4*)(ws + WS_X);
    const float4* wr = (const float4*)(W_ih + (size_t)i * H);
    const float4* wz = (const float4*)(W_ih + (size_t)(H + i) * H);
    const float4* wn = (const float4*)(W_ih + (size_t)(2 * H + i) * H);
    float ar = 0.f, az = 0.f, an = 0.f;
    #pragma unroll
    for (int k = lane; k < H / 4; k += 64) {
        float4 xv = x4[k];
        ar += dot4(xv, wr[k]);
        az += dot4(xv, wz[k]);
        an += dot4(xv, wn[k]);
    }
    ar = wave_sum(ar); az = wave_sum(az); an = wave_sum(an);
    if (lane == 0) {
        float r = 1.f / (1.f + expf(-((ar + b_ih[i]) + ws[WS_GH + i])));
        float z = 1.f / (1.f + expf(-((az + b_ih[H + i]) + ws[WS_GH + H + i])));
        float n = tanhf((an + b_ih[2 * H + i]) + r * ws[WS_GH + 2 * H + i]);
        float hn = (1.f - z) * n + z * hidden[i];
        hnew_out[i] = hn;
        ws[WS_HNEW + i] = hn;
    }
}

// K5: vocab logits, 4 rows per wave (16 per block), fused exp + slot-atomic sum.
__global__ void k5_out(const float* __restrict__ out_W, const float* __restrict__ out_b,
                       float* __restrict__ ws) {
    const int wv = threadIdx.x >> 6, lane = threadIdx.x & 63;
    const int v0 = (blockIdx.x * 4 + wv) * 4;
    __shared__ float se[4];
    const float4* h4 = (const float4*)(ws + WS_HNEW);
    const bool ok0 = v0 < V, ok1 = v0 + 1 < V, ok2 = v0 + 2 < V, ok3 = v0 + 3 < V;
    const float4* r0 = (const float4*)(out_W + (size_t)(ok0 ? v0 : 0) * H);
    const float4* r1 = (const float4*)(out_W + (size_t)(ok1 ? v0 + 1 : 0) * H);
    const float4* r2 = (const float4*)(out_W + (size_t)(ok2 ? v0 + 2 : 0) * H);
    const float4* r3 = (const float4*)(out_W + (size_t)(ok3 ? v0 + 3 : 0) * H);
    float a0 = 0.f, a1 = 0.f, a2 = 0.f, a3 = 0.f;
    #pragma unroll
    for (int k = lane; k < H / 4; k += 64) {
        float4 hv = h4[k];
        a0 += dot4(hv, r0[k]);
        a1 += dot4(hv, r1[k]);
        a2 += dot4(hv, r2[k]);
        a3 += dot4(hv, r3[k]);
    }
    a0 = wave_sum(a0); a1 = wave_sum(a1); a2 = wave_sum(a2); a3 = wave_sum(a3);
    if (lane == 0) {
        float es = 0.f, l;
        if (ok0) { l = a0 + out_b[v0];     ws[WS_LOGITS + v0]     = l; es += expf(l); }
        if (ok1) { l = a1 + out_b[v0 + 1]; ws[WS_LOGITS + v0 + 1] = l; es += expf(l); }
        if (ok2) { l = a2 + out_b[v0 + 2]; ws[WS_LOGITS + v0 + 2] = l; es += expf(l); }
        if (ok3) { l = a3 + out_b[v0 + 3]; ws[WS_LOGITS + v0 + 3] = l; es += expf(l); }
        se[wv] = es;
    }
    __syncthreads();
    if (threadIdx.x == 0)
        atomicAdd(&ws[WS_OSUM + (blockIdx.x & 63)], se[0] + se[1] + se[2] + se[3]);
}

// K6: out[v] = logit[v] - log(sum of 64 slots)
__global__ void k6_lsm(const float* __restrict__ ws, float* __restrict__ out) {
    const int v = blockIdx.x * 256 + threadIdx.x;
    float s = 0.f;
    #pragma unroll
    for (int j = 0; j < 64; ++j) s += ws[WS_OSUM + j];
    if (v < V) out[v] = ws[WS_LOGITS + v] - logf(s);
}

extern "C" void kernel_launch(void* const* d_in, const int* in_sizes, int n_in,
                              void* d_out, int out_size, void* d_ws, size_t ws_size,
                              hipStream_t stream) {
    const int*   tok    = (const int*)d_in[0];
    const float* hidden = (const float*)d_in[1];
    const float* enc    = (const float*)d_in[2];
    const float* emb    = (const float*)d_in[3];
    const float* attn_W = (const float*)d_in[4];
    const float* attn_b = (const float*)d_in[5];
    const float* comb_W = (const float*)d_in[6];
    const float* comb_b = (const float*)d_in[7];
    const float* W_ih   = (const float*)d_in[8];
    const float* W_hh   = (const float*)d_in[9];
    const float* b_ih   = (const float*)d_in[10];
    const float* b_hh   = (const float*)d_in[11];
    const float* out_W  = (const float*)d_in[12];
    const float* out_b  = (const float*)d_in[13];

    float* out       = (float*)d_out;          // [V] log-softmax
    float* out_hnew  = (float*)d_out + V;      // [H]
    float* out_attnw = (float*)d_out + V + H;  // [F]
    float* ws        = (float*)d_ws;

    hipMemsetAsync(d_ws, 0, (size_t)WS_X * sizeof(float), stream);  // accum slots + applied

    k1_attn_gh<<<F / 4 + (3 * H) / 4, 256, 0, stream>>>(tok, hidden, emb, attn_W, attn_b,
                                                        W_hh, b_hh, ws);
    k2_apply<<<dim3(H / 256, F / 32), 256, 0, stream>>>(enc, ws, out_attnw);
    k3_comb<<<H / 4, 256, 0, stream>>>(tok, emb, comb_W, comb_b, ws);
    k4_gru<<<H / 4, 256, 0, stream>>>(hidden, W_ih, b_ih, ws, out_hnew);
    k5_out<<<(V + 15) / 16, 256, 0, stream>>>(out_W, out_b, ws);
    k6_lsm<<<(V + 255) / 256, 256, 0, stream>>>(ws, out);
}

// Round 4
// 415.246 us; speedup vs baseline: 1.0867x; 1.0387x over previous
//
#include <hip/hip_runtime.h>
#include <math.h>

#define H 1024
#define F 2048
#define V 50257

// ws layout (float offsets); [0 .. 5120) floats zeroed by hipMemsetAsync each launch.
// Slot arrays use stride 16 floats (64 B) so each atomic slot owns a cache line.
#define WS_ASUM    0      // [64 slots x16]  attn exp-sum
#define WS_OSUM    1024   // [64 slots x16]  vocab exp-sum
#define WS_EXPW    2048   // [F]   unnormalized attn weights exp(logit)
#define WS_APPLIED 4096   // [H]   attn_applied accumulator (atomics)
#define WS_X       5120   // [H]   combine+relu output
#define WS_HNEW    6144   // [H]   h_new (16B-aligned copy for float4 reads)
#define WS_GH      7168   // [3H]  h @ W_hh.T + b_hh

typedef float floatx4 __attribute__((ext_vector_type(4)));

__device__ __forceinline__ float wave_sum(float v) {
    #pragma unroll
    for (int off = 32; off > 0; off >>= 1) v += __shfl_xor(v, off, 64);
    return v;
}

__device__ __forceinline__ float dot4(float4 a, float4 b) {
    return a.x * b.x + a.y * b.y + a.z * b.z + a.w * b.w;
}

// nontemporal float4 load for stream-once weight matrices (don't pollute L2)
__device__ __forceinline__ float4 ldnt4(const float4* p) {
    floatx4 v = __builtin_nontemporal_load((const floatx4*)p);
    return make_float4(v.x, v.y, v.z, v.w);
}

__device__ __forceinline__ float ldnt1(const float* p) {
    return __builtin_nontemporal_load(p);
}

// K1: fused  [attn logits -> exp -> slot-atomic sum]  (blocks 0..511, wave/row)
//        ||  [gh = h @ W_hh.T + b_hh]                 (blocks 512..1279, wave/row)
__global__ void k1_attn_gh(const int* __restrict__ tok_p, const float* __restrict__ hidden,
                           const float* __restrict__ emb, const float* __restrict__ attn_W,
                           const float* __restrict__ attn_b, const float* __restrict__ W_hh,
                           const float* __restrict__ b_hh, float* __restrict__ ws) {
    const int wv = threadIdx.x >> 6, lane = threadIdx.x & 63;
    const int bid = blockIdx.x;
    const float4* h4 = (const float4*)hidden;
    if (bid < F / 4) {
        __shared__ float se[4];
        const int f = bid * 4 + wv;
        const int tok = tok_p[0];
        const float4* e4 = (const float4*)(emb + (size_t)tok * H);
        const float4* row = (const float4*)(attn_W + (size_t)f * (2 * H));
        float acc = 0.f;
        #pragma unroll
        for (int k = lane; k < H / 4; k += 64)
            acc += dot4(e4[k], ldnt4(&row[k])) + dot4(h4[k], ldnt4(&row[H / 4 + k]));
        acc = wave_sum(acc);
        if (lane == 0) {
            float e = expf(acc + attn_b[f]);
            ws[WS_EXPW + f] = e;
            se[wv] = e;
        }
        __syncthreads();
        if (threadIdx.x == 0)
            atomicAdd(&ws[WS_ASUM + ((bid & 63) << 4)], se[0] + se[1] + se[2] + se[3]);
    } else {
        const int i = (bid - F / 4) * 4 + wv;   // [0, 3H)
        const float4* row = (const float4*)(W_hh + (size_t)i * H);
        float acc = 0.f;
        #pragma unroll
        for (int k = lane; k < H / 4; k += 64) acc += dot4(h4[k], ldnt4(&row[k]));
        acc = wave_sum(acc);
        if (lane == 0) ws[WS_GH + i] = acc + b_hh[i];
    }
}

// K2: applied[h] += (1/sum) * sum_f expw[f]*enc[f,h]; also writes normalized attn weights.
__global__ void k2_apply(const float* __restrict__ enc, float* __restrict__ ws,
                         float* __restrict__ out_attnw) {
    const int h = blockIdx.x * 256 + threadIdx.x;
    const int f0 = blockIdx.y * 32;
    float s = 0.f;
    #pragma unroll
    for (int j = 0; j < 64; ++j) s += ws[WS_ASUM + (j << 4)];
    const float inv = 1.f / s;
    float acc = 0.f;
    #pragma unroll 8
    for (int f = f0; f < f0 + 32; ++f)
        acc += ws[WS_EXPW + f] * ldnt1(&enc[(size_t)f * H + h]);
    atomicAdd(&ws[WS_APPLIED + h], acc * inv);
    if (blockIdx.x == 0 && threadIdx.x < 32) {
        int f = f0 + threadIdx.x;
        out_attnw[f] = ws[WS_EXPW + f] * inv;
    }
}

// K3: x = relu([emb[tok], applied] @ comb_W.T + comb_b), wave/row
__global__ void k3_comb(const int* __restrict__ tok_p, const float* __restrict__ emb,
                        const float* __restrict__ comb_W, const float* __restrict__ comb_b,
                        float* __restrict__ ws) {
    const int wv = threadIdx.x >> 6, lane = threadIdx.x & 63;
    const int i = blockIdx.x * 4 + wv;
    const int tok = tok_p[0];
    const float4* e4 = (const float4*)(emb + (size_t)tok * H);
    const float4* a4 = (const float4*)(ws + WS_APPLIED);
    const float4* row = (const float4*)(comb_W + (size_t)i * (2 * H));
    float acc = 0.f;
    #pragma unroll
    for (int k = lane; k < H / 4; k += 64)
        acc += dot4(e4[k], ldnt4(&row[k])) + dot4(a4[k], ldnt4(&row[H / 4 + k]));
    acc = wave_sum(acc);
    if (lane == 0) ws[WS_X + i] = fmaxf(acc + comb_b[i], 0.f);
}

// K4: gx = x @ W_ih.T; gates with precomputed gh; h_new. Wave per output i.
__global__ void k4_gru(const float* __restrict__ hidden, const float* __restrict__ W_ih,
                       const float* __restrict__ b_ih, float* __restrict__ ws,
                       float* __restrict__ hnew_out) {
    const int wv = threadIdx.x >> 6, lane = threadIdx.x & 63;
    const int i = blockIdx.x * 4 + wv;
    const float4* x4 = (const float4*)(ws + WS_X);
    const float4* wr = (const float4*)(W_ih + (size_t)i * H);
    const float4* wz = (const float4*)(W_ih + (size_t)(H + i) * H);
    const float4* wn = (const float4*)(W_ih + (size_t)(2 * H + i) * H);
    float ar = 0.f, az = 0.f, an = 0.f;
    #pragma unroll
    for (int k = lane; k < H / 4; k += 64) {
        float4 xv = x4[k];
        ar += dot4(xv, ldnt4(&wr[k]));
        az += dot4(xv, ldnt4(&wz[k]));
        an += dot4(xv, ldnt4(&wn[k]));
    }
    ar = wave_sum(ar); az = wave_sum(az); an = wave_sum(an);
    if (lane == 0) {
        float r = 1.f / (1.f + expf(-((ar + b_ih[i]) + ws[WS_GH + i])));
        float z = 1.f / (1.f + expf(-((az + b_ih[H + i]) + ws[WS_GH + H + i])));
        float n = tanhf((an + b_ih[2 * H + i]) + r * ws[WS_GH + 2 * H + i]);
        float hn = (1.f - z) * n + z * hidden[i];
        hnew_out[i] = hn;
        ws[WS_HNEW + i] = hn;
    }
}

// K5: vocab logits straight into d_out, 4 rows/wave, fused exp + slot-atomic sum.
__global__ void k5_out(const float* __restrict__ out_W, const float* __restrict__ out_b,
                       float* __restrict__ ws, float* __restrict__ out) {
    const int wv = threadIdx.x >> 6, lane = threadIdx.x & 63;
    const int v0 = (blockIdx.x * 4 + wv) * 4;
    __shared__ float se[4];
    const float4* h4 = (const float4*)(ws + WS_HNEW);
    const bool ok0 = v0 < V, ok1 = v0 + 1 < V, ok2 = v0 + 2 < V, ok3 = v0 + 3 < V;
    const float4* r0 = (const float4*)(out_W + (size_t)(ok0 ? v0 : 0) * H);
    const float4* r1 = (const float4*)(out_W + (size_t)(ok1 ? v0 + 1 : 0) * H);
    const float4* r2 = (const float4*)(out_W + (size_t)(ok2 ? v0 + 2 : 0) * H);
    const float4* r3 = (const float4*)(out_W + (size_t)(ok3 ? v0 + 3 : 0) * H);
    float a0 = 0.f, a1 = 0.f, a2 = 0.f, a3 = 0.f;
    #pragma unroll
    for (int k = lane; k < H / 4; k += 64) {
        float4 hv = h4[k];
        a0 += dot4(hv, ldnt4(&r0[k]));
        a1 += dot4(hv, ldnt4(&r1[k]));
        a2 += dot4(hv, ldnt4(&r2[k]));
        a3 += dot4(hv, ldnt4(&r3[k]));
    }
    a0 = wave_sum(a0); a1 = wave_sum(a1); a2 = wave_sum(a2); a3 = wave_sum(a3);
    if (lane == 0) {
        float es = 0.f, l;
        if (ok0) { l = a0 + out_b[v0];     out[v0]     = l; es += expf(l); }
        if (ok1) { l = a1 + out_b[v0 + 1]; out[v0 + 1] = l; es += expf(l); }
        if (ok2) { l = a2 + out_b[v0 + 2]; out[v0 + 2] = l; es += expf(l); }
        if (ok3) { l = a3 + out_b[v0 + 3]; out[v0 + 3] = l; es += expf(l); }
        se[wv] = es;
    }
    __syncthreads();
    if (threadIdx.x == 0)
        atomicAdd(&ws[WS_OSUM + ((blockIdx.x & 63) << 4)], se[0] + se[1] + se[2] + se[3]);
}

// K6: out[v] -= log(sum of 64 slots)   (in-place on the logits K5 wrote)
__global__ void k6_lsm(const float* __restrict__ ws, float* __restrict__ out) {
    const int v = blockIdx.x * 256 + threadIdx.x;
    float s = 0.f;
    #pragma unroll
    for (int j = 0; j < 64; ++j) s += ws[WS_OSUM + (j << 4)];
    if (v < V) out[v] -= logf(s);
}

extern "C" void kernel_launch(void* const* d_in, const int* in_sizes, int n_in,
                              void* d_out, int out_size, void* d_ws, size_t ws_size,
                              hipStream_t stream) {
    const int*   tok    = (const int*)d_in[0];
    const float* hidden = (const float*)d_in[1];
    const float* enc    = (const float*)d_in[2];
    const float* emb    = (const float*)d_in[3];
    const float* attn_W = (const float*)d_in[4];
    const float* attn_b = (const float*)d_in[5];
    const float* comb_W = (const float*)d_in[6];
    const float* comb_b = (const float*)d_in[7];
    const float* W_ih   = (const float*)d_in[8];
    const float* W_hh   = (const float*)d_in[9];
    const float* b_ih   = (const float*)d_in[10];
    const float* b_hh   = (const float*)d_in[11];
    const float* out_W  = (const float*)d_in[12];
    const float* out_b  = (const float*)d_in[13];

    float* out       = (float*)d_out;          // [V] log-softmax
    float* out_hnew  = (float*)d_out + V;      // [H]
    float* out_attnw = (float*)d_out + V + H;  // [F]
    float* ws        = (float*)d_ws;

    (void)hipMemsetAsync(d_ws, 0, (size_t)WS_X * sizeof(float), stream);  // slots + applied

    k1_attn_gh<<<F / 4 + (3 * H) / 4, 256, 0, stream>>>(tok, hidden, emb, attn_W, attn_b,
                                                        W_hh, b_hh, ws);
    k2_apply<<<dim3(H / 256, F / 32), 256, 0, stream>>>(enc, ws, out_attnw);
    k3_comb<<<H / 4, 256, 0, stream>>>(tok, emb, comb_W, comb_b, ws);
    k4_gru<<<H / 4, 256, 0, stream>>>(hidden, W_ih, b_ih, ws, out_hnew);
    k5_out<<<(V + 15) / 16, 256, 0, stream>>>(out_W, out_b, ws, out);
    k6_lsm<<<(V + 255) / 256, 256, 0, stream>>>(ws, out);
}